// Round 7
// baseline (171.366 us; speedup 1.0000x reference)
//
#include <hip/hip_runtime.h>
#include <stdint.h>

// HQQ 4-bit dequant + linear (Llama-7B up-proj, decode: 8 tokens)
// OUT=11008, IN=4096, GS=64, G=704512, OC=172 (=G/IN; OUT=64*OC)
// W_q: [32, G] int32; hi nibble -> unpacked row rq, lo -> row rq+32.
// W_r[o,i]: r=o/172, oc=o%172, g=oc*4096+i.
// out[b,o] = sum_i x[b,i] * fma(nib, s[g], -z[g]*s[g]) + bias[o]
//
// R7 theory: R2's VGPR_Count=48 proves the compiler collapsed every
// source-level register pipeline into serial load->use chains (~300cyc/load,
// no overlap => the invariant ~45-55us band). Fix: stage EVERYTHING through
// __builtin_amdgcn_global_load_lds (async DMA, no dest VGPRs, cannot be
// collapsed). m97-style 2-barrier K-loop: x/s/z staged once per block;
// Wq in a double-buffered LDS tile so tile t+1 DMA overlaps tile t compute.
// 16 packed rows/block, KS=8, 52KB LDS -> 3 blocks/CU, 2752 blocks.

#define OUT_ 11008
#define IN_ 4096
#define G_ 704512
#define OC_ 172
#define KS 8              // K-split factor
#define KC (IN_ / KS)     // 512 K per block
#define TILE 256          // K per pipeline stage
#define NT (KC / TILE)    // 2 stages

__device__ __forceinline__ void async_cp16(const void* gsrc, void* ldst) {
    // 16B per lane; LDS dest = wave-uniform base + lane*16 (m104 semantics).
    __builtin_amdgcn_global_load_lds(
        (const __attribute__((address_space(1))) void*)gsrc,
        (__attribute__((address_space(3))) void*)ldst, 16, 0, 0);
}

__global__ __launch_bounds__(256, 3)
void hqq_gemv(const int* __restrict__ Wq, const float* __restrict__ scale,
              const float* __restrict__ zero, const float* __restrict__ x,
              float* __restrict__ ws) {
    __shared__ float x_lds[8 * KC];          // 16 KB  [b][k]
    __shared__ float s_lds[KC];              // 2 KB
    __shared__ float z_lds[KC];              // 2 KB
    __shared__ int   wq_lds[2][16 * TILE];   // 32 KB  [buf][row][k]

    const int lane = threadIdx.x;            // 0..63
    const int ty   = threadIdx.y;            // 0..3 (wave id)
    const int oc   = blockIdx.y;             // 0..171
    const int ks   = blockIdx.z;             // 0..KS-1
    const int rqb  = blockIdx.x * 16;        // first packed row of this block

    const int kbase = ks * KC;
    const long gb = (long)oc * IN_ + kbase;

    // ---- async stage x (16 KB): per wave-issue 1KB contiguous ----
#pragma unroll
    for (int j = 0; j < 4; ++j) {
        const int fl = j * 1024 + ty * 256;      // float idx, wave-uniform
        const int b  = fl >> 9;                  // fl / KC (KC=512)
        const int k  = fl & (KC - 1);
        async_cp16(x + b * IN_ + kbase + k + lane * 4, x_lds + fl);
    }
    // ---- async stage s/z (2+2 KB): one issue, waves 0/1 -> s, 2/3 -> z ----
    {
        const float* src = (ty < 2 ? scale : zero) + gb + (ty & 1) * 256 + lane * 4;
        float*       dst = (ty < 2 ? s_lds : z_lds) + (ty & 1) * 256;
        async_cp16(src, dst);
    }
    // ---- async stage Wq tile 0: LDS row r at offset r*TILE ----
#pragma unroll
    for (int j = 0; j < 4; ++j) {
        const int row = j * 4 + ty;              // wave-uniform
        async_cp16(Wq + (long)(rqb + row) * G_ + gb + lane * 4,
                   &wq_lds[0][row * TILE]);
    }
    __syncthreads();

    // acc[rr*2+0][b] = hi row of (rqb+ty*4+rr), acc[rr*2+1][b] = lo row
    float acc[8][8];
#pragma unroll
    for (int r = 0; r < 8; ++r)
#pragma unroll
        for (int b = 0; b < 8; ++b) acc[r][b] = 0.f;

    const int i0 = lane * 4;

    for (int t = 0; t < NT; ++t) {
        const int buf = t & 1;
        if (t + 1 < NT) {
            // async DMA of tile t+1 — overlaps the compute below
#pragma unroll
            for (int j = 0; j < 4; ++j) {
                const int row = j * 4 + ty;
                async_cp16(Wq + (long)(rqb + row) * G_ + gb + (t + 1) * TILE + lane * 4,
                           &wq_lds[buf ^ 1][row * TILE]);
            }
        }

        const int toff = t * TILE;
        const float4 s4 = *(const float4*)(s_lds + toff + i0);
        const float4 z4 = *(const float4*)(z_lds + toff + i0);
        const float ss[4] = {s4.x, s4.y, s4.z, s4.w};
        const float zs[4] = {-z4.x * s4.x, -z4.y * s4.y, -z4.z * s4.z, -z4.w * s4.w};

        float4 xv[8];
#pragma unroll
        for (int b = 0; b < 8; ++b)
            xv[b] = *(const float4*)(x_lds + b * KC + toff + i0);

#pragma unroll
        for (int rr = 0; rr < 4; ++rr) {
            const int4 q4 = *(const int4*)&wq_lds[buf][(ty * 4 + rr) * TILE + i0];
            const int qs[4] = {q4.x, q4.y, q4.z, q4.w};
            float wh[4], wl[4];
#pragma unroll
            for (int j = 0; j < 4; ++j) {
                wh[j] = fmaf((float)((qs[j] >> 4) & 0xF), ss[j], zs[j]);
                wl[j] = fmaf((float)( qs[j]       & 0xF), ss[j], zs[j]);
            }
#pragma unroll
            for (int b = 0; b < 8; ++b) {
                const float4 xb = xv[b];
                float ah = acc[rr * 2 + 0][b];
                float al = acc[rr * 2 + 1][b];
                ah = fmaf(xb.x, wh[0], ah); al = fmaf(xb.x, wl[0], al);
                ah = fmaf(xb.y, wh[1], ah); al = fmaf(xb.y, wl[1], al);
                ah = fmaf(xb.z, wh[2], ah); al = fmaf(xb.z, wl[2], al);
                ah = fmaf(xb.w, wh[3], ah); al = fmaf(xb.w, wl[3], al);
                acc[rr * 2 + 0][b] = ah;
                acc[rr * 2 + 1][b] = al;
            }
        }

        if (t + 1 < NT) __syncthreads();  // drains DMA of tile t+1, syncs LDS
    }

    // ---- reduce across the 64 K-slice lanes ----
#pragma unroll
    for (int r = 0; r < 8; ++r)
#pragma unroll
        for (int b = 0; b < 8; ++b) {
            float v = acc[r][b];
#pragma unroll
            for (int off = 32; off > 0; off >>= 1)
                v += __shfl_down(v, off, 64);
            acc[r][b] = v;
        }

    if (lane == 0) {
        float* __restrict__ wp = ws + (long)ks * 8 * OUT_;
#pragma unroll
        for (int rr = 0; rr < 4; ++rr) {
            const int rq = rqb + ty * 4 + rr;
            const int o_hi = rq * OC_ + oc;
            const int o_lo = (rq + 32) * OC_ + oc;
#pragma unroll
            for (int b = 0; b < 8; ++b) {
                wp[b * OUT_ + o_hi] = acc[rr * 2 + 0][b];
                wp[b * OUT_ + o_lo] = acc[rr * 2 + 1][b];
            }
        }
    }
}

__global__ void hqq_reduce(const float* __restrict__ ws,
                           const float* __restrict__ bias,
                           float* __restrict__ out) {
    const int t = blockIdx.x * 256 + threadIdx.x;
    if (t >= 8 * OUT_) return;
    const int o = t % OUT_;
    float v = bias[o];
#pragma unroll
    for (int k = 0; k < KS; ++k) v += ws[k * 8 * OUT_ + t];
    out[t] = v;
}

extern "C" void kernel_launch(void* const* d_in, const int* in_sizes, int n_in,
                              void* d_out, int out_size, void* d_ws, size_t ws_size,
                              hipStream_t stream) {
    const int*   Wq    = (const int*)d_in[0];    // [32, 704512] int32
    const float* scale = (const float*)d_in[1];  // [1, 704512]
    const float* zero  = (const float*)d_in[2];  // [1, 704512]
    const float* x     = (const float*)d_in[3];  // [8, 1, 4096]
    const float* bias  = (const float*)d_in[4];  // [11008]
    float* out = (float*)d_out;                  // [8, 1, 11008]
    float* ws  = (float*)d_ws;                   // KS*8*11008 floats = 2.8 MB

    dim3 grid(2, OC_, KS);  // x: 16-packed-row half, y: oc, z: K-split
    dim3 block(64, 4);      // 4 waves; each owns 4 packed rows x 8 batches
    hqq_gemv<<<grid, block, 0, stream>>>(Wq, scale, zero, x, ws);
    hqq_reduce<<<(8 * OUT_ + 255) / 256, 256, 0, stream>>>(ws, bias, out);
}

// Round 8
// 156.106 us; speedup vs baseline: 1.0978x; 1.0978x over previous
//
#include <hip/hip_runtime.h>
#include <stdint.h>

// HQQ 4-bit dequant + linear (Llama-7B up-proj, decode: 8 tokens)
// OUT=11008, IN=4096, GS=64, G=704512, OC=172 (=G/IN; OUT=64*OC)
// W_q: [32, G] int32; hi nibble -> unpacked row rq, lo -> row rq+32.
// W_r[o,i]: r=o/172, oc=o%172, g=oc*4096+i.
// out[b,o] = sum_i x[b,i] * fma(nib, s[g], -z[g]*s[g]) + bias[o]
//
// R8 theory: R7 counters expose two stacked costs: (1) LDS pipe ~256B/cyc/CU
// carried ~22MB/CU, of which ~17MB was the 64-acc x 6-step bpermute epilogue
// (KC=512 -> only 32K MACs amortize it: 3 B LDS-reduce per MAC); (2) VALU
// issue ~23us (34.6% busy). Fix: KS=2 -> KC=2048 per wave (4x epilogue
// amortization, 0.75 B/MAC) with ALL operands (Wq, x, s, z) DMA'd per-tile
// into double-buffered LDS (no VGPR load chains, x needs only 2x8KB).
// 52KB LDS -> 3 blocks/CU; 688 blocks all-resident.

#define OUT_ 11008
#define IN_ 4096
#define G_ 704512
#define OC_ 172
#define KS 2               // K-split factor
#define KC (IN_ / KS)      // 2048 K per block
#define TILE 256           // K per pipeline stage
#define NT (KC / TILE)     // 8 stages

__device__ __forceinline__ void async_cp16(const void* gsrc, void* ldst) {
    // 16B per lane; LDS dest = wave-uniform base + lane*16 (m104 semantics).
    __builtin_amdgcn_global_load_lds(
        (const __attribute__((address_space(1))) void*)gsrc,
        (__attribute__((address_space(3))) void*)ldst, 16, 0, 0);
}

__global__ __launch_bounds__(256, 3)
void hqq_gemv(const int* __restrict__ Wq, const float* __restrict__ scale,
              const float* __restrict__ zero, const float* __restrict__ x,
              float* __restrict__ ws) {
    __shared__ int   wq_lds[2][16 * TILE];   // 32 KB [buf][row][k]
    __shared__ float x_lds[2][8 * TILE];     // 16 KB [buf][b][k]
    __shared__ float s_lds[2][TILE];         // 2 KB
    __shared__ float z_lds[2][TILE];         // 2 KB

    const int lane = threadIdx.x;            // 0..63
    const int ty   = threadIdx.y;            // 0..3 (wave id)
    const int oc   = blockIdx.y;             // 0..171
    const int ks   = blockIdx.z;             // 0..KS-1
    const int rqb  = blockIdx.x * 16;        // first packed row of this block

    const int kbase = ks * KC;
    const long gb = (long)oc * IN_ + kbase;
    const int i0 = lane * 4;

    // ---- stage tile t into buffer buf (pure DMA, wave-uniform LDS bases) ----
    auto stage = [&](int t, int buf) {
        const int koff = t * TILE;
        // Wq: 16 rows x 1KB, 4 issues per wave
#pragma unroll
        for (int j = 0; j < 4; ++j) {
            const int row = j * 4 + ty;
            async_cp16(Wq + (long)(rqb + row) * G_ + gb + koff + i0,
                       &wq_lds[buf][row * TILE]);
        }
        // x: 8 batches x 1KB, 2 issues per wave
#pragma unroll
        for (int j = 0; j < 2; ++j) {
            const int b = ty * 2 + j;
            async_cp16(x + b * IN_ + kbase + koff + i0, &x_lds[buf][b * TILE]);
        }
        // s/z: 1KB each, waves 0 and 1
        if (ty == 0) async_cp16(scale + gb + koff + i0, &s_lds[buf][0]);
        if (ty == 1) async_cp16(zero + gb + koff + i0, &z_lds[buf][0]);
    };

    // acc[rr*2+0][b] = hi row of (rqb+ty*4+rr), acc[rr*2+1][b] = lo row
    float acc[8][8];
#pragma unroll
    for (int r = 0; r < 8; ++r)
#pragma unroll
        for (int b = 0; b < 8; ++b) acc[r][b] = 0.f;

    stage(0, 0);
    __syncthreads();

    int buf = 0;
    for (int t = 0; t < NT; ++t) {
        if (t + 1 < NT) stage(t + 1, buf ^ 1);  // DMA overlaps compute below

        const float4 s4 = *(const float4*)(&s_lds[buf][i0]);
        const float4 z4 = *(const float4*)(&z_lds[buf][i0]);
        const float ss[4] = {s4.x, s4.y, s4.z, s4.w};
        const float zs[4] = {-z4.x * s4.x, -z4.y * s4.y, -z4.z * s4.z, -z4.w * s4.w};

        float4 xv[8];
#pragma unroll
        for (int b = 0; b < 8; ++b)
            xv[b] = *(const float4*)(&x_lds[buf][b * TILE + i0]);

#pragma unroll
        for (int rr = 0; rr < 4; ++rr) {
            const int4 q4 = *(const int4*)&wq_lds[buf][(ty * 4 + rr) * TILE + i0];
            const int qs[4] = {q4.x, q4.y, q4.z, q4.w};
            float wh[4], wl[4];
#pragma unroll
            for (int j = 0; j < 4; ++j) {
                wh[j] = fmaf((float)((qs[j] >> 4) & 0xF), ss[j], zs[j]);
                wl[j] = fmaf((float)( qs[j]       & 0xF), ss[j], zs[j]);
            }
#pragma unroll
            for (int b = 0; b < 8; ++b) {
                const float4 xb = xv[b];
                float ah = acc[rr * 2 + 0][b];
                float al = acc[rr * 2 + 1][b];
                ah = fmaf(xb.x, wh[0], ah); al = fmaf(xb.x, wl[0], al);
                ah = fmaf(xb.y, wh[1], ah); al = fmaf(xb.y, wl[1], al);
                ah = fmaf(xb.z, wh[2], ah); al = fmaf(xb.z, wl[2], al);
                ah = fmaf(xb.w, wh[3], ah); al = fmaf(xb.w, wl[3], al);
                acc[rr * 2 + 0][b] = ah;
                acc[rr * 2 + 1][b] = al;
            }
        }

        __syncthreads();  // drains tile t+1 DMA; protects buf reuse
        buf ^= 1;
    }

    // ---- reduce across the 64 K-slice lanes (amortized over KC=2048) ----
#pragma unroll
    for (int r = 0; r < 8; ++r)
#pragma unroll
        for (int b = 0; b < 8; ++b) {
            float v = acc[r][b];
#pragma unroll
            for (int off = 32; off > 0; off >>= 1)
                v += __shfl_down(v, off, 64);
            acc[r][b] = v;
        }

    if (lane == 0) {
        float* __restrict__ wp = ws + (long)ks * 8 * OUT_;
#pragma unroll
        for (int rr = 0; rr < 4; ++rr) {
            const int rq = rqb + ty * 4 + rr;
            const int o_hi = rq * OC_ + oc;
            const int o_lo = (rq + 32) * OC_ + oc;
#pragma unroll
            for (int b = 0; b < 8; ++b) {
                wp[b * OUT_ + o_hi] = acc[rr * 2 + 0][b];
                wp[b * OUT_ + o_lo] = acc[rr * 2 + 1][b];
            }
        }
    }
}

__global__ void hqq_reduce(const float* __restrict__ ws,
                           const float* __restrict__ bias,
                           float* __restrict__ out) {
    const int t = blockIdx.x * 256 + threadIdx.x;
    if (t >= 8 * OUT_) return;
    const int o = t % OUT_;
    float v = bias[o];
#pragma unroll
    for (int k = 0; k < KS; ++k) v += ws[k * 8 * OUT_ + t];
    out[t] = v;
}

extern "C" void kernel_launch(void* const* d_in, const int* in_sizes, int n_in,
                              void* d_out, int out_size, void* d_ws, size_t ws_size,
                              hipStream_t stream) {
    const int*   Wq    = (const int*)d_in[0];    // [32, 704512] int32
    const float* scale = (const float*)d_in[1];  // [1, 704512]
    const float* zero  = (const float*)d_in[2];  // [1, 704512]
    const float* x     = (const float*)d_in[3];  // [8, 1, 4096]
    const float* bias  = (const float*)d_in[4];  // [11008]
    float* out = (float*)d_out;                  // [8, 1, 11008]
    float* ws  = (float*)d_ws;                   // KS*8*11008 floats = 704 KB

    dim3 grid(2, OC_, KS);  // x: 16-packed-row half, y: oc, z: K-split
    dim3 block(64, 4);      // 4 waves; each owns 4 packed rows x 8 batches
    hqq_gemv<<<grid, block, 0, stream>>>(Wq, scale, zero, x, ws);
    hqq_reduce<<<(8 * OUT_ + 255) / 256, 256, 0, stream>>>(ws, bias, out);
}